// Round 10
// baseline (203.783 us; speedup 1.0000x reference)
//
#include <hip/hip_runtime.h>

#define N_ 4096
#define M_ 10
#define T_ 10
#define B_ 1024
#define P_ 1024
#define NBLK 256
#define NTHR 512

__device__ __forceinline__ float wave_red_sum(float v) {
#pragma unroll
  for (int m = 32; m >= 1; m >>= 1) v += __shfl_xor(v, m);
  return v;
}

// Agent-scope bypass accessors (coherence-point served; no cache maintenance).
__device__ __forceinline__ float gld(const float* p) {
  return __hip_atomic_load(p, __ATOMIC_RELAXED, __HIP_MEMORY_SCOPE_AGENT);
}
__device__ __forceinline__ void gst(float* p, float v) {
  __hip_atomic_store(p, v, __ATOMIC_RELAXED, __HIP_MEMORY_SCOPE_AGENT);
}
__device__ __forceinline__ unsigned ld_u(unsigned* p) {
  return __hip_atomic_load(p, __ATOMIC_RELAXED, __HIP_MEMORY_SCOPE_AGENT);
}

__device__ __forceinline__ void drain_sync() {
  asm volatile("s_waitcnt vmcnt(0)" ::: "memory");
  __syncthreads();
}
__device__ __forceinline__ void signal(unsigned* slot, unsigned val) {
  if (threadIdx.x == 0)
    __hip_atomic_store(slot, val, __ATOMIC_RELAXED, __HIP_MEMORY_SCOPE_AGENT);
}
// Wait until slots[0..n) all >= target. Wave 0 scans; __all over 64 lanes.
__device__ __forceinline__ void wait_set(unsigned* slots, int n, unsigned target) {
  if (threadIdx.x < 64) {
    int lane = threadIdx.x;
    bool ok;
    do {
      ok = true;
      for (int i = lane; i < n; i += 64) ok &= (ld_u(&slots[i]) >= target);
      ok = __all(ok);
      if (!ok) __builtin_amdgcn_s_sleep(1);
    } while (!ok);
  }
  __syncthreads();
}

__global__ void k_init(unsigned* __restrict__ bar) {
  if (threadIdx.x < 1024)
    __hip_atomic_store(bar + threadIdx.x, 0u, __ATOMIC_RELAXED, __HIP_MEMORY_SCOPE_AGENT);
}

struct MArgs {
  const float *x, *post0, *pre0;
  const int* pairs;
  const float* decay;
  const float *iew1, *ieb1, *ieg1, *iebe1, *iew2, *ieb2, *ieg2, *iebe2, *iew3, *ieb3;
  const float *syw1, *syb1, *syg, *sybe, *syw2, *syb2;
  const float *nw1, *nb1, *ng, *nbe, *nw2, *nb2;
  const float *vw, *vb;
  const float *rdw1, *rdb1, *rdg1, *rdbe1, *rdw2, *rdb2, *rdg2, *rdbe2, *rdw3, *rdb3;
  float *pc, *pc2, *enc_g, *hbar, *postG, *scp;
  float* out;
  unsigned* bar;
};

// ONE persistent mega-kernel. 256 blocks x 512 threads, 1 block/CU (~150 KB LDS).
// Block g: neurons [16g,16g+16) (nm_w1 / syw1 rows / syw2 cols pinned in LDS),
// batch rows [4g,4g+4) (encoder + readout), ONE hbar column (j = g).
// Tick: slotA(all) -> strips(wait ALL, race-safe) -> slotR -> all{cval,stats,
// mb/rb,own col} -> slotC -> all{npre,nm,pc}. 3 hops/tick.
__global__ __launch_bounds__(NTHR)
void k_mega(MArgs a) {
  const int g = blockIdx.x, tid = threadIdx.x;
  const int lane = tid & 63;
  const int n0 = g * 16, b0e = g * 4;

  __shared__ float s_w1[16 * M_ * 128];   // 80 KB nm_w1 slice [nl][m][j]
  __shared__ float s_syw1[16 * 256];      // 16 KB sy_w1 rows 4+n0..
  __shared__ float s_w4[4 * 256];         // 4 KB sy_w1 rows 0..3
  __shared__ float s_syw2[256 * 16];      // 16 KB syw2 cols n0..n0+16 [k][nl]
  __shared__ float reg1[4096];            // fx | encT[b][4] | r1+p2
  __shared__ float reg2[1024];            // e1/e2/encs | r2
  __shared__ float s_mbrb[2048];          // [b][2] interleaved m, r
  __shared__ float s_values[4][64];
  __shared__ float s_post[16][M_];
  __shared__ float s_pre[16][M_];
  __shared__ float s_pl[16];
  __shared__ float s_hbar[256];
  __shared__ float s_cval[256];
  __shared__ float s_tmp[2][256];
  __shared__ float s_stats[20];           // [0..5] tick, [6..19] static

  unsigned* slotA = a.bar;          // 256 words
  unsigned* slotR = a.bar + 256;    // 8 words (strips)
  unsigned* slotC = a.bar + 320;    // 256 words (hbar columns)

  // ================= PROLOGUE ===============================================
  {
    const float4* src = (const float4*)(a.nw1 + n0 * M_ * 128);
    float4* dst = (float4*)s_w1;
    for (int i = tid; i < 16 * M_ * 128 / 4; i += NTHR) dst[i] = src[i];
    const float4* s2 = (const float4*)(a.syw1 + (4 + n0) * 256);
    float4* d2 = (float4*)s_syw1;
    for (int i = tid; i < 16 * 256 / 4; i += NTHR) d2[i] = s2[i];
    const float4* s3 = (const float4*)a.syw1;
    float4* d3 = (float4*)s_w4;
    for (int i = tid; i < 1024 / 4; i += NTHR) d3[i] = s3[i];
    for (int i = tid; i < 256 * 4; i += NTHR) {  // syw2 slice [k][16]
      int k = i >> 2, part = i & 3;
      *(float4*)&s_syw2[k * 16 + part * 4] =
          *(const float4*)&a.syw2[k * N_ + n0 + part * 4];
    }
    if (tid < 160) {
      int r = tid / 10, m = tid - r * 10;
      s_post[r][m] = a.post0[(n0 + r) * M_ + m];
      s_pre[r][m]  = a.pre0[(n0 + r) * M_ + m];
    }
    for (int i = tid; i < 4 * 784; i += NTHR) reg1[i] = a.x[b0e * 784 + i];
  }
  __syncthreads();
  if (tid < 16) s_pl[tid] = s_post[tid][M_ - 1];

  {  // encoder E1: 4 rows x 128 j
    int r = tid >> 7, j = tid & 127;
    float u = a.ieb1[j];
    const float* fxr = reg1 + r * 784;
    for (int k = 0; k < 784; ++k) u += fxr[k] * a.iew1[k * 128 + j];
    float s = wave_red_sum(u), sq = wave_red_sum(u * u);
    int w = tid >> 6;
    if (lane == 0) { s_tmp[0][w] = s; s_tmp[1][w] = sq; }
    __syncthreads();
    float S = s_tmp[0][r * 2] + s_tmp[0][r * 2 + 1];
    float S2 = s_tmp[1][r * 2] + s_tmp[1][r * 2 + 1];
    float mm = S * (1.f / 128.f), vv = S2 * (1.f / 128.f) - mm * mm;
    reg2[r * 128 + j] = fmaxf((u - mm) * rsqrtf(vv + 1e-5f) * a.ieg1[j] + a.iebe1[j], 0.f);
  }
  __syncthreads();
  if (tid < 128) {  // E2: 4 rows x 32, LN32 via width-32 shuffles
    int r = tid >> 5, jj = tid & 31;
    float u = a.ieb2[jj];
    for (int k = 0; k < 128; ++k) u += reg2[r * 128 + k] * a.iew2[k * 32 + jj];
    float ss = u, sq = u * u;
#pragma unroll
    for (int m = 16; m >= 1; m >>= 1) { ss += __shfl_xor(ss, m, 32); sq += __shfl_xor(sq, m, 32); }
    float mm = ss * (1.f / 32.f), vv = sq * (1.f / 32.f) - mm * mm;
    reg2[512 + r * 32 + jj] = fmaxf((u - mm) * rsqrtf(vv + 1e-5f) * a.ieg2[jj] + a.iebe2[jj], 0.f);
  }
  __syncthreads();
  if (tid < 16) {  // enc 4x4
    int r = tid >> 2, o = tid & 3;
    float u = a.ieb3[o];
    for (int k = 0; k < 32; ++k) u += reg2[512 + r * 32 + k] * a.iew3[k * 4 + o];
    reg2[640 + r * 4 + o] = u;
    gst(&a.enc_g[(b0e + r) * 4 + o], u);
  }
  __syncthreads();
  if (tid < 256) {  // values (softmax over size-1 axis == 1 -> att == values)
    int r = tid >> 6, v = tid & 63;
    float u = a.vb[v];
#pragma unroll
    for (int o = 0; o < 4; ++o) u += reg2[640 + r * 4 + o] * a.vw[o * 64 + v];
    s_values[r][v] = u;
  }
  __syncthreads();
  {  // first pc partial (pinned syw1)
    int j = tid & 255, half = tid >> 8;
    float acc = 0.f;
#pragma unroll
    for (int r = 0; r < 8; ++r) {
      int n = half * 8 + r;
      acc += s_pl[n] * s_syw1[n * 256 + j];
    }
    s_tmp[half][j] = acc;
  }
  __syncthreads();
  if (tid < 256) gst(&a.pc[g * 256 + tid], s_tmp[0][tid] + s_tmp[1][tid]);
  drain_sync();
  signal(&slotA[g], 1u);

  {  // static w4 moments (block-local, overlaps hop propagation)
    float q[14];
    if (tid < 256) {
      float wv[4] = {s_w4[tid], s_w4[256 + tid], s_w4[512 + tid], s_w4[768 + tid]};
      int idx = 0;
#pragma unroll
      for (int o = 0; o < 4; ++o) q[idx++] = wv[o];
#pragma unroll
      for (int o = 0; o < 4; ++o)
#pragma unroll
        for (int p = 0; p <= o; ++p) q[idx++] = wv[o] * wv[p];
    } else {
#pragma unroll
      for (int i = 0; i < 14; ++i) q[i] = 0.f;
    }
#pragma unroll
    for (int i = 0; i < 14; ++i) q[i] = wave_red_sum(q[i]);
    int w = tid >> 6;
    if (lane == 0) {
#pragma unroll
      for (int i = 0; i < 14; ++i) s_tmp[1][w * 16 + i] = q[i];
    }
    __syncthreads();
    if (tid < 14) {
      float S = 0.f;
#pragma unroll
      for (int w2 = 0; w2 < 8; ++w2) S += s_tmp[1][w2 * 16 + tid];
      s_stats[6 + tid] = S * (1.f / 256.f);
    }
  }
  __syncthreads();

  // ================= TICK LOOP ==============================================
  for (int t = 0; t < T_; ++t) {
    // strips: block s<8 reduces pc rows r = s + 8i -> pc2[s][256].
    // Wait ALL 256 (not just own producers): guarantees every block finished
    // mid(t-1)'s pc2 reads before overwrite (race fix).
    if (g < 8) {
      wait_set(slotA, 256, (unsigned)(t + 1));
      int j = tid & 255, half = tid >> 8;
      float acc = 0.f;
#pragma unroll
      for (int i = 0; i < 16; ++i) {
        int r = g + 8 * (half * 16 + i);
        acc += gld(&a.pc[r * 256 + j]);
      }
      s_tmp[half][j] = acc;
      __syncthreads();
      if (tid < 256) gst(&a.pc2[g * 256 + tid], s_tmp[0][tid] + s_tmp[1][tid]);
      drain_sync();
      signal(&slotR[g], (unsigned)(t + 1));
    }
    // everyone: cval + tick stats + mb/rb + own hbar column
    wait_set(slotR, 8, (unsigned)(t + 1));
    if (t == 0) {  // encT[b][4] = straight copy of enc_g
      for (int i = tid; i < 4096; i += NTHR) reg1[i] = gld(&a.enc_g[i]);
    }
    {  // cval gather: 512 threads, 4 strips each
      int j = tid & 255, half = tid >> 8;
      float cp = 0.f;
#pragma unroll
      for (int s = 0; s < 4; ++s) cp += gld(&a.pc2[(half * 4 + s) * 256 + j]);
      s_tmp[half][j] = cp;
    }
    __syncthreads();
    {
      float cv = 0.f;
      if (tid < 256) {
        cv = a.syb1[tid] + s_tmp[0][tid] + s_tmp[1][tid];
        s_cval[tid] = cv;
      }
      float p[6];
      if (tid < 256) {
        p[0] = cv; p[1] = cv * cv;
        p[2] = cv * s_w4[tid]; p[3] = cv * s_w4[256 + tid];
        p[4] = cv * s_w4[512 + tid]; p[5] = cv * s_w4[768 + tid];
      } else {
#pragma unroll
        for (int i = 0; i < 6; ++i) p[i] = 0.f;
      }
      __syncthreads();  // all s_tmp reads done before lane0 rewrites below
#pragma unroll
      for (int i = 0; i < 6; ++i) p[i] = wave_red_sum(p[i]);
      int w = tid >> 6;
      if (lane == 0) {
#pragma unroll
        for (int i = 0; i < 6; ++i) s_tmp[0][w * 8 + i] = p[i];
      }
      __syncthreads();
      if (tid < 6) {
        float S = 0.f;
#pragma unroll
        for (int w2 = 0; w2 < 8; ++w2) S += s_tmp[0][w2 * 8 + tid];
        s_stats[tid] = S * (1.f / 256.f);
      }
      __syncthreads();
    }
    {  // mb/rb for all 1024 b, float4 encT + interleaved store
#pragma unroll
      for (int h2 = 0; h2 < 2; ++h2) {
        int b = h2 * 512 + tid;
        float4 e = *(const float4*)&reg1[b * 4];
        float m = s_stats[0] + e.x * s_stats[6] + e.y * s_stats[7] + e.z * s_stats[8] + e.w * s_stats[9];
        float eu2 = s_stats[1] + 2.f * (e.x * s_stats[2] + e.y * s_stats[3] + e.z * s_stats[4] + e.w * s_stats[5]);
        float qf = e.x * e.x * s_stats[10]
                 + 2.f * e.y * e.x * s_stats[11] + e.y * e.y * s_stats[12]
                 + 2.f * e.z * e.x * s_stats[13] + 2.f * e.z * e.y * s_stats[14] + e.z * e.z * s_stats[15]
                 + 2.f * e.w * e.x * s_stats[16] + 2.f * e.w * e.y * s_stats[17]
                 + 2.f * e.w * e.z * s_stats[18] + e.w * e.w * s_stats[19];
        eu2 += qf;
        s_mbrb[b * 2] = m;
        s_mbrb[b * 2 + 1] = rsqrtf(eu2 - m * m + 1e-5f);
      }
      __syncthreads();
    }
    {  // own hbar column j = g
      float cj = s_cval[g];
      float w0 = s_w4[g], w1v = s_w4[256 + g], w2v = s_w4[512 + g], w3v = s_w4[768 + g];
      float gj = a.syg[g], bj = a.sybe[g];
      float acc = 0.f;
#pragma unroll
      for (int h2 = 0; h2 < 2; ++h2) {
        int b = h2 * 512 + tid;
        float4 e = *(const float4*)&reg1[b * 4];
        float u = cj + e.x * w0 + e.y * w1v + e.z * w2v + e.w * w3v;
        float y = (u - s_mbrb[b * 2]) * s_mbrb[b * 2 + 1] * gj + bj;
        acc += fmaxf(y, 0.f);
      }
      acc = wave_red_sum(acc);
      int w = tid >> 6;
      if (lane == 0) s_tmp[0][w] = acc;
      __syncthreads();
      if (tid == 0) {
        float S = 0.f;
#pragma unroll
        for (int w2 = 0; w2 < 8; ++w2) S += s_tmp[0][w2];
        gst(&a.hbar[g], S * (1.f / 1024.f));
      }
    }
    drain_sync();
    signal(&slotC[g], (unsigned)(t + 1));
    // everyone: wait full hbar, then P3
    wait_set(slotC, 256, (unsigned)(t + 1));
    if (tid < 256) s_hbar[tid] = gld(&a.hbar[tid]);
    __syncthreads();
    {  // npre from pinned syw2; s_tmp as [32][16]
      int nl = tid & 15, kq = tid >> 4;
      float u = 0.f;
#pragma unroll
      for (int kk = 0; kk < 8; ++kk) {
        int k = kq * 8 + kk;
        u += s_hbar[k] * s_syw2[k * 16 + nl];
      }
      ((float*)s_tmp)[kq * 16 + nl] = u;
    }
    __syncthreads();
    if (tid < 16) {
      float v = a.syb2[n0 + tid];
#pragma unroll
      for (int q2 = 0; q2 < 32; ++q2) v += ((float*)s_tmp)[q2 * 16 + tid];
#pragma unroll
      for (int m = 0; m < M_ - 1; ++m) s_pre[tid][m] = s_pre[tid][m + 1];
      s_pre[tid][M_ - 1] = v;
    }
    __syncthreads();
    {  // nm: 16 neurons x 32 lanes, 4 CONTIGUOUS j per lane (float4 LDS reads)
      int nl = tid >> 5, q = tid & 31;
      int n2 = n0 + nl;
      int jb = q * 4;
      float pr[M_];
#pragma unroll
      for (int m = 0; m < M_; ++m) pr[m] = s_pre[nl][m];
      float4 uu = *(const float4*)&a.nb1[n2 * 128 + jb];
#pragma unroll
      for (int m = 0; m < M_; ++m) {
        float4 w = *(const float4*)&s_w1[(nl * M_ + m) * 128 + jb];
        uu.x += pr[m] * w.x; uu.y += pr[m] * w.y;
        uu.z += pr[m] * w.z; uu.w += pr[m] * w.w;
      }
      float s = uu.x + uu.y + uu.z + uu.w;
      float sq = uu.x * uu.x + uu.y * uu.y + uu.z * uu.z + uu.w * uu.w;
#pragma unroll
      for (int m = 16; m >= 1; m >>= 1) { s += __shfl_xor(s, m, 32); sq += __shfl_xor(sq, m, 32); }
      float mm = s * (1.f / 128.f), vv = sq * (1.f / 128.f) - mm * mm;
      float ri = rsqrtf(vv + 1e-5f);
      float4 gg = *(const float4*)&a.ng[n2 * 128 + jb];
      float4 be = *(const float4*)&a.nbe[n2 * 128 + jb];
      float4 w2v = *(const float4*)&a.nw2[n2 * 128 + jb];
      float y0 = fmaxf((uu.x - mm) * ri * gg.x + be.x, 0.f);
      float y1 = fmaxf((uu.y - mm) * ri * gg.y + be.y, 0.f);
      float y2 = fmaxf((uu.z - mm) * ri * gg.z + be.z, 0.f);
      float y3 = fmaxf((uu.w - mm) * ri * gg.w + be.w, 0.f);
      float d = y0 * w2v.x + y1 * w2v.y + y2 * w2v.z + y3 * w2v.w;
#pragma unroll
      for (int m = 16; m >= 1; m >>= 1) d += __shfl_xor(d, m, 32);
      if (q == 0) {
        float npost = d + a.nb2[n2];
#pragma unroll
        for (int m = 0; m < M_ - 1; ++m) s_post[nl][m] = s_post[nl][m + 1];
        s_post[nl][M_ - 1] = npost;
        s_pl[nl] = npost;
      }
    }
    __syncthreads();
    if (t < T_ - 1) {  // next pc partial
      int j = tid & 255, half = tid >> 8;
      float acc = 0.f;
#pragma unroll
      for (int r = 0; r < 8; ++r) {
        int n = half * 8 + r;
        acc += s_pl[n] * s_syw1[n * 256 + j];
      }
      s_tmp[half][j] = acc;
      __syncthreads();
      if (tid < 256) gst(&a.pc[g * 256 + tid], s_tmp[0][tid] + s_tmp[1][tid]);
    } else {  // flush final post rows
      if (tid < 160) {
        int r = tid / 10, m = tid - r * 10;
        gst(&a.postG[(n0 + r) * M_ + m], s_post[r][m]);
      }
    }
    drain_sync();
    signal(&slotA[g], (unsigned)(t + 2));
  }

  // ================= EPILOGUE ===============================================
  // strips: syncv (own 128 pairs) + scp partial in one stage
  if (g < 8) {
    wait_set(slotA, 256, 11u);
    if (tid < 128) {
      int p = g * 128 + tid;
      int i = a.pairs[p * 2], jn = a.pairs[p * 2 + 1];
      float dc = a.decay[p];
      float num = 0.f, den = 0.f;
#pragma unroll
      for (int l = 0; l < M_; ++l) {
        float r = expf(-dc * (float)(M_ - 1 - l));
        num += gld(&a.postG[i * M_ + l]) * r * gld(&a.postG[jn * M_ + l]);
        den += r;
      }
      s_tmp[0][tid] = num / (den + 1e-8f);
    }
    __syncthreads();
    float acc = 0.f;
    for (int i = 0; i < 128; ++i)
      acc += s_tmp[0][i] * a.rdw1[(64 + g * 128 + i) * 512 + tid];
    gst(&a.scp[g * 512 + tid], acc);
    drain_sync();
    signal(&slotR[g], 11u);
  }
  wait_set(slotR, 8, 11u);
  {  // readout for own 4 batch rows
    float* r1 = reg1;
    float* p2 = reg1 + 2048;
    float base = a.rdb1[tid];
#pragma unroll
    for (int s = 0; s < 8; ++s) base += gld(&a.scp[s * 512 + tid]);
    float u[4];
#pragma unroll
    for (int r = 0; r < 4; ++r) u[r] = base;
    for (int k = 0; k < 64; ++k) {
      float w = a.rdw1[k * 512 + tid];
#pragma unroll
      for (int r = 0; r < 4; ++r) u[r] += s_values[r][k] * w;
    }
    int wid = tid >> 6;
#pragma unroll
    for (int r = 0; r < 4; ++r) {
      float s = wave_red_sum(u[r]), sq = wave_red_sum(u[r] * u[r]);
      if (lane == 0) { s_tmp[0][r * 8 + wid] = s; s_tmp[1][r * 8 + wid] = sq; }
    }
    __syncthreads();
    float gg = a.rdg1[tid], bb = a.rdbe1[tid];
#pragma unroll
    for (int r = 0; r < 4; ++r) {
      float S = 0.f, S2 = 0.f;
#pragma unroll
      for (int w = 0; w < 8; ++w) { S += s_tmp[0][r * 8 + w]; S2 += s_tmp[1][r * 8 + w]; }
      float m = S * (1.f / 512.f), v = S2 * (1.f / 512.f) - m * m;
      r1[r * 512 + tid] = fmaxf((u[r] - m) * rsqrtf(v + 1e-5f) * gg + bb, 0.f);
    }
    __syncthreads();
    int o = tid & 63, kq = tid >> 6;
    float u2[4] = {0.f, 0.f, 0.f, 0.f};
#pragma unroll
    for (int kk = 0; kk < 64; ++kk) {
      int k = kq * 64 + kk;
      float w = a.rdw2[k * 64 + o];
#pragma unroll
      for (int r = 0; r < 4; ++r) u2[r] += r1[r * 512 + k] * w;
    }
#pragma unroll
    for (int r = 0; r < 4; ++r) p2[(kq * 4 + r) * 64 + o] = u2[r];
    __syncthreads();
    if (tid < 256) {
      int r = tid >> 6, o2 = tid & 63;
      float v = a.rdb2[o2];
#pragma unroll
      for (int q = 0; q < 8; ++q) v += p2[(q * 4 + r) * 64 + o2];
      float s = wave_red_sum(v), sq = wave_red_sum(v * v);
      float m = s * (1.f / 64.f), var = sq * (1.f / 64.f) - m * m;
      reg2[r * 64 + o2] = fmaxf((v - m) * rsqrtf(var + 1e-5f) * a.rdg2[o2] + a.rdbe2[o2], 0.f);
    }
    __syncthreads();
    if (tid < 40) {
      int r = tid / 10, o3 = tid - r * 10;
      float acc = a.rdb3[o3];
#pragma unroll
      for (int k = 0; k < 64; ++k) acc += reg2[r * 64 + k] * a.rdw3[k * 10 + o3];
      a.out[(b0e + r) * 10 + o3] = acc;
    }
  }
}

extern "C" void kernel_launch(void* const* d_in, const int* in_sizes, int n_in,
                              void* d_out, int out_size, void* d_ws, size_t ws_size,
                              hipStream_t stream) {
  MArgs a;
  a.x     = (const float*)d_in[0];
  a.post0 = (const float*)d_in[1];
  a.pre0  = (const float*)d_in[2];
  a.pairs = (const int*)d_in[3];
  a.decay = (const float*)d_in[4];
  a.iew1  = (const float*)d_in[5];
  a.ieb1  = (const float*)d_in[6];
  a.ieg1  = (const float*)d_in[7];
  a.iebe1 = (const float*)d_in[8];
  a.iew2  = (const float*)d_in[9];
  a.ieb2  = (const float*)d_in[10];
  a.ieg2  = (const float*)d_in[11];
  a.iebe2 = (const float*)d_in[12];
  a.iew3  = (const float*)d_in[13];
  a.ieb3  = (const float*)d_in[14];
  a.syw1  = (const float*)d_in[15];
  a.syb1  = (const float*)d_in[16];
  a.syg   = (const float*)d_in[17];
  a.sybe  = (const float*)d_in[18];
  a.syw2  = (const float*)d_in[19];
  a.syb2  = (const float*)d_in[20];
  a.nw1   = (const float*)d_in[21];
  a.nb1   = (const float*)d_in[22];
  a.ng    = (const float*)d_in[23];
  a.nbe   = (const float*)d_in[24];
  a.nw2   = (const float*)d_in[25];
  a.nb2   = (const float*)d_in[26];
  a.vw    = (const float*)d_in[29];
  a.vb    = (const float*)d_in[30];
  a.rdw1  = (const float*)d_in[33];
  a.rdb1  = (const float*)d_in[34];
  a.rdg1  = (const float*)d_in[35];
  a.rdbe1 = (const float*)d_in[36];
  a.rdw2  = (const float*)d_in[37];
  a.rdb2  = (const float*)d_in[38];
  a.rdg2  = (const float*)d_in[39];
  a.rdbe2 = (const float*)d_in[40];
  a.rdw3  = (const float*)d_in[41];
  a.rdb3  = (const float*)d_in[42];
  a.out = (float*)d_out;

  float* ws = (float*)d_ws;
  a.pc    = ws;                 // 65536
  a.pc2   = ws + 65536;         // 2048
  a.enc_g = ws + 67584;         // 4096
  a.hbar  = ws + 71680;         // 256
  a.postG = ws + 71936;         // 40960
  a.scp   = ws + 112896;        // 4096
  a.bar   = (unsigned*)(ws + 117000);  // 1024 uints

  k_init<<<1, 1024, 0, stream>>>(a.bar);
  k_mega<<<NBLK, NTHR, 0, stream>>>(a);
}

// Round 11
// 198.435 us; speedup vs baseline: 1.0269x; 1.0269x over previous
//
#include <hip/hip_runtime.h>

#define N_ 4096
#define M_ 10
#define T_ 10
#define B_ 1024
#define P_ 1024
#define NBLK 256
#define NTHR 512

__device__ __forceinline__ float wave_red_sum(float v) {
#pragma unroll
  for (int m = 32; m >= 1; m >>= 1) v += __shfl_xor(v, m);
  return v;
}

// Agent-scope bypass accessors (coherence-point served; no cache maintenance).
__device__ __forceinline__ float gld(const float* p) {
  return __hip_atomic_load(p, __ATOMIC_RELAXED, __HIP_MEMORY_SCOPE_AGENT);
}
__device__ __forceinline__ void gst(float* p, float v) {
  __hip_atomic_store(p, v, __ATOMIC_RELAXED, __HIP_MEMORY_SCOPE_AGENT);
}
__device__ __forceinline__ unsigned ld_u(unsigned* p) {
  return __hip_atomic_load(p, __ATOMIC_RELAXED, __HIP_MEMORY_SCOPE_AGENT);
}

__device__ __forceinline__ void drain_sync() {
  asm volatile("s_waitcnt vmcnt(0)" ::: "memory");
  __syncthreads();
}
__device__ __forceinline__ void signal(unsigned* slot, unsigned val) {
  if (threadIdx.x == 0)
    __hip_atomic_store(slot, val, __ATOMIC_RELAXED, __HIP_MEMORY_SCOPE_AGENT);
}
// Wait until slots[0..n) all >= target. Wave 0 scans; __all over 64 lanes.
__device__ __forceinline__ void wait_set(unsigned* slots, int n, unsigned target) {
  if (threadIdx.x < 64) {
    int lane = threadIdx.x;
    bool ok;
    do {
      ok = true;
      for (int i = lane; i < n; i += 64) ok &= (ld_u(&slots[i]) >= target);
      ok = __all(ok);
      if (!ok) __builtin_amdgcn_s_sleep(1);
    } while (!ok);
  }
  __syncthreads();
}
// Wait until slots[s + 8*i] >= target for i in [0,32). SAFE (transitivity):
// producer X signals slotA=t+2 only after its P3(t), which starts only after
// slotC(t) from ALL 256 blocks, each of which signals slotC only after its
// pc2 reads in mid(t) completed. So own-32 wait covers the pc2 WAR hazard.
__device__ __forceinline__ void wait_mod8(unsigned* slots, int s, unsigned target) {
  if (threadIdx.x < 64) {
    int lane = threadIdx.x;
    bool ok;
    do {
      ok = (lane < 32) ? (ld_u(&slots[s + 8 * lane]) >= target) : true;
      ok = __all(ok);
      if (!ok) __builtin_amdgcn_s_sleep(1);
    } while (!ok);
  }
  __syncthreads();
}

__global__ void k_init(unsigned* __restrict__ bar) {
  if (threadIdx.x < 1024)
    __hip_atomic_store(bar + threadIdx.x, 0u, __ATOMIC_RELAXED, __HIP_MEMORY_SCOPE_AGENT);
}

struct MArgs {
  const float *x, *post0, *pre0;
  const int* pairs;
  const float* decay;
  const float *iew1, *ieb1, *ieg1, *iebe1, *iew2, *ieb2, *ieg2, *iebe2, *iew3, *ieb3;
  const float *syw1, *syb1, *syg, *sybe, *syw2, *syb2;
  const float *nw1, *nb1, *ng, *nbe, *nw2, *nb2;
  const float *vw, *vb;
  const float *rdw1, *rdb1, *rdg1, *rdbe1, *rdw2, *rdb2, *rdg2, *rdbe2, *rdw3, *rdb3;
  float *pc, *pc2, *enc_g, *hbar, *postG, *scp;
  float* out;
  unsigned* bar;
};

// ONE persistent mega-kernel. 256 blocks x 512 threads, 1 block/CU (~150 KB LDS).
// Block g: neurons [16g,16g+16) (nm_w1 / syw1 rows / syw2 cols pinned in LDS),
// batch rows [4g,4g+4) (encoder + readout), ONE hbar column (j = g).
// Tick: slotA(all) -> strips(own-32) -> slotR -> all{cval,stats,mb/rb,own col}
// -> slotC -> all{npre,nm,pc}. 3 hops/tick. All lane-axis LDS accesses stride-1
// (bank-conflict-free; round-10's per-lane float4 was a 4-way conflict).
__global__ __launch_bounds__(NTHR)
void k_mega(MArgs a) {
  const int g = blockIdx.x, tid = threadIdx.x;
  const int lane = tid & 63;
  const int n0 = g * 16, b0e = g * 4;

  __shared__ float s_w1[16 * M_ * 128];   // 80 KB nm_w1 slice [nl][m][j]
  __shared__ float s_syw1[16 * 256];      // 16 KB sy_w1 rows 4+n0..
  __shared__ float s_w4[4 * 256];         // 4 KB sy_w1 rows 0..3
  __shared__ float s_syw2[256 * 16];      // 16 KB syw2 cols n0.. [k][nl]
  __shared__ float reg1[4096];            // fx | encT[o][b] | r1+p2
  __shared__ float reg2[1024];            // e1/e2/encs | r2
  __shared__ float s_mbrb[2048];          // mb[1024], rb[1024]
  __shared__ float s_values[4][64];
  __shared__ float s_post[16][M_];
  __shared__ float s_pre[16][M_];
  __shared__ float s_pl[16];
  __shared__ float s_hbar[256];
  __shared__ float s_cval[256];
  __shared__ float s_tmp[2][256];
  __shared__ float s_stats[20];           // [0..5] tick, [6..19] static

  unsigned* slotA = a.bar;          // 256 words
  unsigned* slotR = a.bar + 256;    // 8 words (strips)
  unsigned* slotC = a.bar + 320;    // 256 words (hbar columns)

  // ================= PROLOGUE ===============================================
  {
    const float4* src = (const float4*)(a.nw1 + n0 * M_ * 128);
    float4* dst = (float4*)s_w1;
    for (int i = tid; i < 16 * M_ * 128 / 4; i += NTHR) dst[i] = src[i];
    const float4* s2 = (const float4*)(a.syw1 + (4 + n0) * 256);
    float4* d2 = (float4*)s_syw1;
    for (int i = tid; i < 16 * 256 / 4; i += NTHR) d2[i] = s2[i];
    const float4* s3 = (const float4*)a.syw1;
    float4* d3 = (float4*)s_w4;
    for (int i = tid; i < 1024 / 4; i += NTHR) d3[i] = s3[i];
    for (int i = tid; i < 256 * 4; i += NTHR) {  // syw2 slice [k][16]
      int k = i >> 2, part = i & 3;
      *(float4*)&s_syw2[k * 16 + part * 4] =
          *(const float4*)&a.syw2[k * N_ + n0 + part * 4];
    }
    if (tid < 160) {
      int r = tid / 10, m = tid - r * 10;
      s_post[r][m] = a.post0[(n0 + r) * M_ + m];
      s_pre[r][m]  = a.pre0[(n0 + r) * M_ + m];
    }
    for (int i = tid; i < 4 * 784; i += NTHR) reg1[i] = a.x[b0e * 784 + i];
  }
  __syncthreads();
  if (tid < 16) s_pl[tid] = s_post[tid][M_ - 1];

  {  // encoder E1: 4 rows x 128 j
    int r = tid >> 7, j = tid & 127;
    float u = a.ieb1[j];
    const float* fxr = reg1 + r * 784;
    for (int k = 0; k < 784; ++k) u += fxr[k] * a.iew1[k * 128 + j];
    float s = wave_red_sum(u), sq = wave_red_sum(u * u);
    int w = tid >> 6;
    if (lane == 0) { s_tmp[0][w] = s; s_tmp[1][w] = sq; }
    __syncthreads();
    float S = s_tmp[0][r * 2] + s_tmp[0][r * 2 + 1];
    float S2 = s_tmp[1][r * 2] + s_tmp[1][r * 2 + 1];
    float mm = S * (1.f / 128.f), vv = S2 * (1.f / 128.f) - mm * mm;
    reg2[r * 128 + j] = fmaxf((u - mm) * rsqrtf(vv + 1e-5f) * a.ieg1[j] + a.iebe1[j], 0.f);
  }
  __syncthreads();
  if (tid < 128) {  // E2: 4 rows x 32, LN32 via width-32 shuffles
    int r = tid >> 5, jj = tid & 31;
    float u = a.ieb2[jj];
    for (int k = 0; k < 128; ++k) u += reg2[r * 128 + k] * a.iew2[k * 32 + jj];
    float ss = u, sq = u * u;
#pragma unroll
    for (int m = 16; m >= 1; m >>= 1) { ss += __shfl_xor(ss, m, 32); sq += __shfl_xor(sq, m, 32); }
    float mm = ss * (1.f / 32.f), vv = sq * (1.f / 32.f) - mm * mm;
    reg2[512 + r * 32 + jj] = fmaxf((u - mm) * rsqrtf(vv + 1e-5f) * a.ieg2[jj] + a.iebe2[jj], 0.f);
  }
  __syncthreads();
  if (tid < 16) {  // enc 4x4
    int r = tid >> 2, o = tid & 3;
    float u = a.ieb3[o];
    for (int k = 0; k < 32; ++k) u += reg2[512 + r * 32 + k] * a.iew3[k * 4 + o];
    reg2[640 + r * 4 + o] = u;
    gst(&a.enc_g[(b0e + r) * 4 + o], u);
  }
  __syncthreads();
  if (tid < 256) {  // values (softmax over size-1 axis == 1 -> att == values)
    int r = tid >> 6, v = tid & 63;
    float u = a.vb[v];
#pragma unroll
    for (int o = 0; o < 4; ++o) u += reg2[640 + r * 4 + o] * a.vw[o * 64 + v];
    s_values[r][v] = u;
  }
  __syncthreads();
  {  // first pc partial (pinned syw1)
    int j = tid & 255, half = tid >> 8;
    float acc = 0.f;
#pragma unroll
    for (int r = 0; r < 8; ++r) {
      int n = half * 8 + r;
      acc += s_pl[n] * s_syw1[n * 256 + j];
    }
    s_tmp[half][j] = acc;
  }
  __syncthreads();
  if (tid < 256) gst(&a.pc[g * 256 + tid], s_tmp[0][tid] + s_tmp[1][tid]);
  drain_sync();
  signal(&slotA[g], 1u);

  {  // static w4 moments (block-local, overlaps hop propagation)
    float q[14];
    if (tid < 256) {
      float wv[4] = {s_w4[tid], s_w4[256 + tid], s_w4[512 + tid], s_w4[768 + tid]};
      int idx = 0;
#pragma unroll
      for (int o = 0; o < 4; ++o) q[idx++] = wv[o];
#pragma unroll
      for (int o = 0; o < 4; ++o)
#pragma unroll
        for (int p = 0; p <= o; ++p) q[idx++] = wv[o] * wv[p];
    } else {
#pragma unroll
      for (int i = 0; i < 14; ++i) q[i] = 0.f;
    }
#pragma unroll
    for (int i = 0; i < 14; ++i) q[i] = wave_red_sum(q[i]);
    int w = tid >> 6;
    if (lane == 0) {
#pragma unroll
      for (int i = 0; i < 14; ++i) s_tmp[1][w * 16 + i] = q[i];
    }
    __syncthreads();
    if (tid < 14) {
      float S = 0.f;
#pragma unroll
      for (int w2 = 0; w2 < 8; ++w2) S += s_tmp[1][w2 * 16 + tid];
      s_stats[6 + tid] = S * (1.f / 256.f);
    }
  }
  __syncthreads();

  // ================= TICK LOOP ==============================================
  for (int t = 0; t < T_; ++t) {
    // strips: block s<8 reduces pc rows r = s + 8i -> pc2[s][256]
    if (g < 8) {
      wait_mod8(slotA, g, (unsigned)(t + 1));
      int j = tid & 255, half = tid >> 8;
      float acc = 0.f;
#pragma unroll
      for (int i = 0; i < 16; ++i) {
        int r = g + 8 * (half * 16 + i);
        acc += gld(&a.pc[r * 256 + j]);
      }
      s_tmp[half][j] = acc;
      __syncthreads();
      if (tid < 256) gst(&a.pc2[g * 256 + tid], s_tmp[0][tid] + s_tmp[1][tid]);
      drain_sync();
      signal(&slotR[g], (unsigned)(t + 1));
    }
    // everyone: cval + tick stats + mb/rb + own hbar column
    wait_set(slotR, 8, (unsigned)(t + 1));
    if (t == 0) {  // encT[o][b] layout: lane-axis stride-1 (conflict-free)
      for (int i = tid; i < 4096; i += NTHR) {
        int b = i >> 2, o = i & 3;
        reg1[o * 1024 + b] = gld(&a.enc_g[i]);
      }
    }
    {  // cval gather: 512 threads, 4 strips each
      int j = tid & 255, half = tid >> 8;
      float cp = 0.f;
#pragma unroll
      for (int s = 0; s < 4; ++s) cp += gld(&a.pc2[(half * 4 + s) * 256 + j]);
      s_tmp[half][j] = cp;
    }
    __syncthreads();
    {
      float cv = 0.f;
      if (tid < 256) {
        cv = a.syb1[tid] + s_tmp[0][tid] + s_tmp[1][tid];
        s_cval[tid] = cv;
      }
      float p[6];
      if (tid < 256) {
        p[0] = cv; p[1] = cv * cv;
        p[2] = cv * s_w4[tid]; p[3] = cv * s_w4[256 + tid];
        p[4] = cv * s_w4[512 + tid]; p[5] = cv * s_w4[768 + tid];
      } else {
#pragma unroll
        for (int i = 0; i < 6; ++i) p[i] = 0.f;
      }
      __syncthreads();  // all s_tmp reads done before lane0 rewrites below
#pragma unroll
      for (int i = 0; i < 6; ++i) p[i] = wave_red_sum(p[i]);
      int w = tid >> 6;
      if (lane == 0) {
#pragma unroll
        for (int i = 0; i < 6; ++i) s_tmp[0][w * 8 + i] = p[i];
      }
      __syncthreads();
      if (tid < 6) {
        float S = 0.f;
#pragma unroll
        for (int w2 = 0; w2 < 8; ++w2) S += s_tmp[0][w2 * 8 + tid];
        s_stats[tid] = S * (1.f / 256.f);
      }
      __syncthreads();
    }
    {  // mb/rb for all 1024 b (2 per thread), encT[o][b] reads
#pragma unroll
      for (int h2 = 0; h2 < 2; ++h2) {
        int b = h2 * 512 + tid;
        float e0 = reg1[b], e1v = reg1[1024 + b], e2v = reg1[2048 + b], e3v = reg1[3072 + b];
        float m = s_stats[0] + e0 * s_stats[6] + e1v * s_stats[7] + e2v * s_stats[8] + e3v * s_stats[9];
        float eu2 = s_stats[1] + 2.f * (e0 * s_stats[2] + e1v * s_stats[3] + e2v * s_stats[4] + e3v * s_stats[5]);
        float qf = e0 * e0 * s_stats[10]
                 + 2.f * e1v * e0 * s_stats[11] + e1v * e1v * s_stats[12]
                 + 2.f * e2v * e0 * s_stats[13] + 2.f * e2v * e1v * s_stats[14] + e2v * e2v * s_stats[15]
                 + 2.f * e3v * e0 * s_stats[16] + 2.f * e3v * e1v * s_stats[17]
                 + 2.f * e3v * e2v * s_stats[18] + e3v * e3v * s_stats[19];
        eu2 += qf;
        s_mbrb[b] = m;
        s_mbrb[1024 + b] = rsqrtf(eu2 - m * m + 1e-5f);
      }
      __syncthreads();
    }
    {  // own hbar column j = g
      float cj = s_cval[g];
      float w0 = s_w4[g], w1v = s_w4[256 + g], w2v = s_w4[512 + g], w3v = s_w4[768 + g];
      float gj = a.syg[g], bj = a.sybe[g];
      float acc = 0.f;
#pragma unroll
      for (int h2 = 0; h2 < 2; ++h2) {
        int b = h2 * 512 + tid;
        float e0 = reg1[b], e1v = reg1[1024 + b], e2v = reg1[2048 + b], e3v = reg1[3072 + b];
        float u = cj + e0 * w0 + e1v * w1v + e2v * w2v + e3v * w3v;
        float y = (u - s_mbrb[b]) * s_mbrb[1024 + b] * gj + bj;
        acc += fmaxf(y, 0.f);
      }
      acc = wave_red_sum(acc);
      int w = tid >> 6;
      if (lane == 0) s_tmp[0][w] = acc;
      __syncthreads();
      if (tid == 0) {
        float S = 0.f;
#pragma unroll
        for (int w2 = 0; w2 < 8; ++w2) S += s_tmp[0][w2];
        gst(&a.hbar[g], S * (1.f / 1024.f));
      }
    }
    drain_sync();
    signal(&slotC[g], (unsigned)(t + 1));
    // everyone: wait full hbar, then P3
    wait_set(slotC, 256, (unsigned)(t + 1));
    if (tid < 256) s_hbar[tid] = gld(&a.hbar[tid]);
    __syncthreads();
    {  // npre from pinned syw2; s_tmp as [32][16]
      int nl = tid & 15, kq = tid >> 4;
      float u = 0.f;
#pragma unroll
      for (int kk = 0; kk < 8; ++kk) {
        int k = kq * 8 + kk;
        u += s_hbar[k] * s_syw2[k * 16 + nl];
      }
      ((float*)s_tmp)[kq * 16 + nl] = u;
    }
    __syncthreads();
    if (tid < 16) {
      float v = a.syb2[n0 + tid];
#pragma unroll
      for (int q2 = 0; q2 < 32; ++q2) v += ((float*)s_tmp)[q2 * 16 + tid];
#pragma unroll
      for (int m = 0; m < M_ - 1; ++m) s_pre[tid][m] = s_pre[tid][m + 1];
      s_pre[tid][M_ - 1] = v;
    }
    __syncthreads();
    {  // nm: 16 neurons x 32 lanes, STRIDED j = q + 32k (conflict-free)
      int nl = tid >> 5, q = tid & 31;
      int n2 = n0 + nl;
      float pr[M_];
#pragma unroll
      for (int m = 0; m < M_; ++m) pr[m] = s_pre[nl][m];
      float u[4];
#pragma unroll
      for (int k = 0; k < 4; ++k) {
        int j = q + 32 * k;
        float uu = a.nb1[n2 * 128 + j];
#pragma unroll
        for (int m = 0; m < M_; ++m) uu += pr[m] * s_w1[(nl * M_ + m) * 128 + j];
        u[k] = uu;
      }
      float s = u[0] + u[1] + u[2] + u[3];
      float sq = u[0] * u[0] + u[1] * u[1] + u[2] * u[2] + u[3] * u[3];
#pragma unroll
      for (int m = 16; m >= 1; m >>= 1) { s += __shfl_xor(s, m, 32); sq += __shfl_xor(sq, m, 32); }
      float mm = s * (1.f / 128.f), vv = sq * (1.f / 128.f) - mm * mm;
      float ri = rsqrtf(vv + 1e-5f);
      float d = 0.f;
#pragma unroll
      for (int k = 0; k < 4; ++k) {
        int j = q + 32 * k;
        float y = fmaxf((u[k] - mm) * ri * a.ng[n2 * 128 + j] + a.nbe[n2 * 128 + j], 0.f);
        d += y * a.nw2[n2 * 128 + j];
      }
#pragma unroll
      for (int m = 16; m >= 1; m >>= 1) d += __shfl_xor(d, m, 32);
      if (q == 0) {
        float npost = d + a.nb2[n2];
#pragma unroll
        for (int m = 0; m < M_ - 1; ++m) s_post[nl][m] = s_post[nl][m + 1];
        s_post[nl][M_ - 1] = npost;
        s_pl[nl] = npost;
      }
    }
    __syncthreads();
    if (t < T_ - 1) {  // next pc partial
      int j = tid & 255, half = tid >> 8;
      float acc = 0.f;
#pragma unroll
      for (int r = 0; r < 8; ++r) {
        int n = half * 8 + r;
        acc += s_pl[n] * s_syw1[n * 256 + j];
      }
      s_tmp[half][j] = acc;
      __syncthreads();
      if (tid < 256) gst(&a.pc[g * 256 + tid], s_tmp[0][tid] + s_tmp[1][tid]);
    } else {  // flush final post rows
      if (tid < 160) {
        int r = tid / 10, m = tid - r * 10;
        gst(&a.postG[(n0 + r) * M_ + m], s_post[r][m]);
      }
    }
    drain_sync();
    signal(&slotA[g], (unsigned)(t + 2));
  }

  // ================= EPILOGUE ===============================================
  // strips: syncv (own 128 pairs) + scp partial in one stage
  if (g < 8) {
    wait_set(slotA, 256, 11u);
    if (tid < 128) {
      int p = g * 128 + tid;
      int i = a.pairs[p * 2], jn = a.pairs[p * 2 + 1];
      float dc = a.decay[p];
      float num = 0.f, den = 0.f;
#pragma unroll
      for (int l = 0; l < M_; ++l) {
        float r = expf(-dc * (float)(M_ - 1 - l));
        num += gld(&a.postG[i * M_ + l]) * r * gld(&a.postG[jn * M_ + l]);
        den += r;
      }
      s_tmp[0][tid] = num / (den + 1e-8f);
    }
    __syncthreads();
    float acc = 0.f;
    for (int i = 0; i < 128; ++i)
      acc += s_tmp[0][i] * a.rdw1[(64 + g * 128 + i) * 512 + tid];
    gst(&a.scp[g * 512 + tid], acc);
    drain_sync();
    signal(&slotR[g], 11u);
  }
  wait_set(slotR, 8, 11u);
  {  // readout for own 4 batch rows
    float* r1 = reg1;
    float* p2 = reg1 + 2048;
    float base = a.rdb1[tid];
#pragma unroll
    for (int s = 0; s < 8; ++s) base += gld(&a.scp[s * 512 + tid]);
    float u[4];
#pragma unroll
    for (int r = 0; r < 4; ++r) u[r] = base;
    for (int k = 0; k < 64; ++k) {
      float w = a.rdw1[k * 512 + tid];
#pragma unroll
      for (int r = 0; r < 4; ++r) u[r] += s_values[r][k] * w;
    }
    int wid = tid >> 6;
#pragma unroll
    for (int r = 0; r < 4; ++r) {
      float s = wave_red_sum(u[r]), sq = wave_red_sum(u[r] * u[r]);
      if (lane == 0) { s_tmp[0][r * 8 + wid] = s; s_tmp[1][r * 8 + wid] = sq; }
    }
    __syncthreads();
    float gg = a.rdg1[tid], bb = a.rdbe1[tid];
#pragma unroll
    for (int r = 0; r < 4; ++r) {
      float S = 0.f, S2 = 0.f;
#pragma unroll
      for (int w = 0; w < 8; ++w) { S += s_tmp[0][r * 8 + w]; S2 += s_tmp[1][r * 8 + w]; }
      float m = S * (1.f / 512.f), v = S2 * (1.f / 512.f) - m * m;
      r1[r * 512 + tid] = fmaxf((u[r] - m) * rsqrtf(v + 1e-5f) * gg + bb, 0.f);
    }
    __syncthreads();
    int o = tid & 63, kq = tid >> 6;
    float u2[4] = {0.f, 0.f, 0.f, 0.f};
#pragma unroll
    for (int kk = 0; kk < 64; ++kk) {
      int k = kq * 64 + kk;
      float w = a.rdw2[k * 64 + o];
#pragma unroll
      for (int r = 0; r < 4; ++r) u2[r] += r1[r * 512 + k] * w;
    }
#pragma unroll
    for (int r = 0; r < 4; ++r) p2[(kq * 4 + r) * 64 + o] = u2[r];
    __syncthreads();
    if (tid < 256) {
      int r = tid >> 6, o2 = tid & 63;
      float v = a.rdb2[o2];
#pragma unroll
      for (int q = 0; q < 8; ++q) v += p2[(q * 4 + r) * 64 + o2];
      float s = wave_red_sum(v), sq = wave_red_sum(v * v);
      float m = s * (1.f / 64.f), var = sq * (1.f / 64.f) - m * m;
      reg2[r * 64 + o2] = fmaxf((v - m) * rsqrtf(var + 1e-5f) * a.rdg2[o2] + a.rdbe2[o2], 0.f);
    }
    __syncthreads();
    if (tid < 40) {
      int r = tid / 10, o3 = tid - r * 10;
      float acc = a.rdb3[o3];
#pragma unroll
      for (int k = 0; k < 64; ++k) acc += reg2[r * 64 + k] * a.rdw3[k * 10 + o3];
      a.out[(b0e + r) * 10 + o3] = acc;
    }
  }
}

extern "C" void kernel_launch(void* const* d_in, const int* in_sizes, int n_in,
                              void* d_out, int out_size, void* d_ws, size_t ws_size,
                              hipStream_t stream) {
  MArgs a;
  a.x     = (const float*)d_in[0];
  a.post0 = (const float*)d_in[1];
  a.pre0  = (const float*)d_in[2];
  a.pairs = (const int*)d_in[3];
  a.decay = (const float*)d_in[4];
  a.iew1  = (const float*)d_in[5];
  a.ieb1  = (const float*)d_in[6];
  a.ieg1  = (const float*)d_in[7];
  a.iebe1 = (const float*)d_in[8];
  a.iew2  = (const float*)d_in[9];
  a.ieb2  = (const float*)d_in[10];
  a.ieg2  = (const float*)d_in[11];
  a.iebe2 = (const float*)d_in[12];
  a.iew3  = (const float*)d_in[13];
  a.ieb3  = (const float*)d_in[14];
  a.syw1  = (const float*)d_in[15];
  a.syb1  = (const float*)d_in[16];
  a.syg   = (const float*)d_in[17];
  a.sybe  = (const float*)d_in[18];
  a.syw2  = (const float*)d_in[19];
  a.syb2  = (const float*)d_in[20];
  a.nw1   = (const float*)d_in[21];
  a.nb1   = (const float*)d_in[22];
  a.ng    = (const float*)d_in[23];
  a.nbe   = (const float*)d_in[24];
  a.nw2   = (const float*)d_in[25];
  a.nb2   = (const float*)d_in[26];
  a.vw    = (const float*)d_in[29];
  a.vb    = (const float*)d_in[30];
  a.rdw1  = (const float*)d_in[33];
  a.rdb1  = (const float*)d_in[34];
  a.rdg1  = (const float*)d_in[35];
  a.rdbe1 = (const float*)d_in[36];
  a.rdw2  = (const float*)d_in[37];
  a.rdb2  = (const float*)d_in[38];
  a.rdg2  = (const float*)d_in[39];
  a.rdbe2 = (const float*)d_in[40];
  a.rdw3  = (const float*)d_in[41];
  a.rdb3  = (const float*)d_in[42];
  a.out = (float*)d_out;

  float* ws = (float*)d_ws;
  a.pc    = ws;                 // 65536
  a.pc2   = ws + 65536;         // 2048
  a.enc_g = ws + 67584;         // 4096
  a.hbar  = ws + 71680;         // 256
  a.postG = ws + 71936;         // 40960
  a.scp   = ws + 112896;        // 4096
  a.bar   = (unsigned*)(ws + 117000);  // 1024 uints

  k_init<<<1, 1024, 0, stream>>>(a.bar);
  k_mega<<<NBLK, NTHR, 0, stream>>>(a);
}

// Round 12
// 197.889 us; speedup vs baseline: 1.0298x; 1.0028x over previous
//
#include <hip/hip_runtime.h>

#define N_ 4096
#define M_ 10
#define T_ 10
#define B_ 1024
#define P_ 1024
#define NBLK 256
#define NTHR 512

__device__ __forceinline__ float wave_red_sum(float v) {
#pragma unroll
  for (int m = 32; m >= 1; m >>= 1) v += __shfl_xor(v, m);
  return v;
}

// Agent-scope bypass accessors (coherence-point served; no cache maintenance).
__device__ __forceinline__ float gld(const float* p) {
  return __hip_atomic_load(p, __ATOMIC_RELAXED, __HIP_MEMORY_SCOPE_AGENT);
}
__device__ __forceinline__ void gst(float* p, float v) {
  __hip_atomic_store(p, v, __ATOMIC_RELAXED, __HIP_MEMORY_SCOPE_AGENT);
}
__device__ __forceinline__ unsigned ld_u(unsigned* p) {
  return __hip_atomic_load(p, __ATOMIC_RELAXED, __HIP_MEMORY_SCOPE_AGENT);
}

__device__ __forceinline__ void drain_sync() {
  asm volatile("s_waitcnt vmcnt(0)" ::: "memory");
  __syncthreads();
}
__device__ __forceinline__ void signal(unsigned* slot, unsigned val) {
  if (threadIdx.x == 0)
    __hip_atomic_store(slot, val, __ATOMIC_RELAXED, __HIP_MEMORY_SCOPE_AGENT);
}
// Wait until slots[0..n) all >= target. Wave 0 scans; __all over 64 lanes.
__device__ __forceinline__ void wait_set(unsigned* slots, int n, unsigned target) {
  if (threadIdx.x < 64) {
    int lane = threadIdx.x;
    bool ok;
    do {
      ok = true;
      for (int i = lane; i < n; i += 64) ok &= (ld_u(&slots[i]) >= target);
      ok = __all(ok);
      if (!ok) __builtin_amdgcn_s_sleep(1);
    } while (!ok);
  }
  __syncthreads();
}
// Wait until slots[s + 8*i] >= target for i in [0,32). SAFE (transitivity):
// producers signal slotA(t+2) only after P3(t), which follows the all-248
// slotC(t) wait, and each slotC signaler finished its pc2 reads in mid(t).
__device__ __forceinline__ void wait_mod8(unsigned* slots, int s, unsigned target) {
  if (threadIdx.x < 64) {
    int lane = threadIdx.x;
    bool ok;
    do {
      ok = (lane < 32) ? (ld_u(&slots[s + 8 * lane]) >= target) : true;
      ok = __all(ok);
      if (!ok) __builtin_amdgcn_s_sleep(1);
    } while (!ok);
  }
  __syncthreads();
}

__global__ void k_init(unsigned* __restrict__ bar) {
  if (threadIdx.x < 1024)
    __hip_atomic_store(bar + threadIdx.x, 0u, __ATOMIC_RELAXED, __HIP_MEMORY_SCOPE_AGENT);
}

struct MArgs {
  const float *x, *post0, *pre0;
  const int* pairs;
  const float* decay;
  const float *iew1, *ieb1, *ieg1, *iebe1, *iew2, *ieb2, *ieg2, *iebe2, *iew3, *ieb3;
  const float *syw1, *syb1, *syg, *sybe, *syw2, *syb2;
  const float *nw1, *nb1, *ng, *nbe, *nw2, *nb2;
  const float *vw, *vb;
  const float *rdw1, *rdb1, *rdg1, *rdbe1, *rdw2, *rdb2, *rdg2, *rdbe2, *rdw3, *rdb3;
  float *pc, *pc2, *enc_g, *hbar, *postG, *scp;
  float* out;
  unsigned* bar;
};

// ONE persistent mega-kernel. 256 blocks x 512 threads, 1 block/CU (~152 KB LDS).
// Block g: neurons [16g,16g+16) (nm_w1 / syw1 rows / syw2 cols pinned in LDS),
// batch rows [4g,4g+4) (encoder + readout).
// hbar columns: blocks 8..255 produce col j=g; blocks 8..15 also produce j=g-8.
// Strips (g<8) do ONLY the pc->pc2 reduce per tick (no mid stage) -> fastest,
// not stragglers. Tick: slotA -> strips -> slotR -> mid(248 blocks) -> slotC ->
// all{npre,nm,pc}. Prologue: first-pc signaled BEFORE heavy pin+encoder.
__global__ __launch_bounds__(NTHR)
void k_mega(MArgs a) {
  const int g = blockIdx.x, tid = threadIdx.x;
  const int lane = tid & 63;
  const int n0 = g * 16, b0e = g * 4;

  __shared__ float s_w1[16 * M_ * 128];   // 80 KB nm_w1 slice [nl][m][j]
  __shared__ float s_syw1[16 * 256];      // 16 KB sy_w1 rows 4+n0..
  __shared__ float s_w4[4 * 256];         // 4 KB sy_w1 rows 0..3
  __shared__ float s_syw2[256 * 17];      // 17 KB syw2 cols n0.. [k][nl] pad-17
  __shared__ float reg1[4096];            // fx | encT[o][b] | r1+p2
  __shared__ float reg2[1024];            // e1/e2/encs | r2
  __shared__ float s_mbrb[2048];          // mb[1024], rb[1024]
  __shared__ float s_values[4][64];
  __shared__ float s_post[16][M_];
  __shared__ float s_pre[16][M_];
  __shared__ float s_pl[16];
  __shared__ float s_hbar[256];
  __shared__ float s_cval[256];
  __shared__ float s_tmp[2][256];
  __shared__ float s_stats[20];           // [0..5] tick, [6..19] static

  unsigned* slotA = a.bar;          // 256 words
  unsigned* slotR = a.bar + 256;    // 8 words (strips)
  unsigned* slotC = a.bar + 320;    // 256 words (cols; 8..255 used)
  unsigned* slotE = a.bar + 576;    // 256 words (encoder done)

  // ===== PROLOGUE stage 0: minimal path to first pc ========================
  {
    const float4* s2 = (const float4*)(a.syw1 + (4 + n0) * 256);
    float4* d2 = (float4*)s_syw1;
    for (int i = tid; i < 16 * 256 / 4; i += NTHR) d2[i] = s2[i];
    if (tid < 160) {
      int r = tid / 10, m = tid - r * 10;
      s_post[r][m] = a.post0[(n0 + r) * M_ + m];
      s_pre[r][m]  = a.pre0[(n0 + r) * M_ + m];
    }
  }
  __syncthreads();
  if (tid < 16) s_pl[tid] = s_post[tid][M_ - 1];
  __syncthreads();
  {
    int j = tid & 255, half = tid >> 8;
    float acc = 0.f;
#pragma unroll
    for (int r = 0; r < 8; ++r) {
      int n = half * 8 + r;
      acc += s_pl[n] * s_syw1[n * 256 + j];
    }
    s_tmp[half][j] = acc;
  }
  __syncthreads();
  if (tid < 256) gst(&a.pc[g * 256 + tid], s_tmp[0][tid] + s_tmp[1][tid]);
  drain_sync();
  signal(&slotA[g], 1u);

  // ===== PROLOGUE stage 1: heavy pins + encoder (off tick-0 critical path) ==
  {
    const float4* src = (const float4*)(a.nw1 + n0 * M_ * 128);
    float4* dst = (float4*)s_w1;
    for (int i = tid; i < 16 * M_ * 128 / 4; i += NTHR) dst[i] = src[i];
    const float4* s3 = (const float4*)a.syw1;
    float4* d3 = (float4*)s_w4;
    for (int i = tid; i < 1024 / 4; i += NTHR) d3[i] = s3[i];
    for (int i = tid; i < 1024; i += NTHR) {  // syw2 slice [k][17-padded]
      int k = i >> 2, part = i & 3;
      float4 v = *(const float4*)&a.syw2[k * N_ + n0 + part * 4];
      s_syw2[k * 17 + part * 4 + 0] = v.x;
      s_syw2[k * 17 + part * 4 + 1] = v.y;
      s_syw2[k * 17 + part * 4 + 2] = v.z;
      s_syw2[k * 17 + part * 4 + 3] = v.w;
    }
    for (int i = tid; i < 4 * 784; i += NTHR) reg1[i] = a.x[b0e * 784 + i];
  }
  __syncthreads();
  {  // encoder E1: 4 rows x 128 j
    int r = tid >> 7, j = tid & 127;
    float u = a.ieb1[j];
    const float* fxr = reg1 + r * 784;
    for (int k = 0; k < 784; ++k) u += fxr[k] * a.iew1[k * 128 + j];
    float s = wave_red_sum(u), sq = wave_red_sum(u * u);
    int w = tid >> 6;
    if (lane == 0) { s_tmp[0][w] = s; s_tmp[1][w] = sq; }
    __syncthreads();
    float S = s_tmp[0][r * 2] + s_tmp[0][r * 2 + 1];
    float S2 = s_tmp[1][r * 2] + s_tmp[1][r * 2 + 1];
    float mm = S * (1.f / 128.f), vv = S2 * (1.f / 128.f) - mm * mm;
    reg2[r * 128 + j] = fmaxf((u - mm) * rsqrtf(vv + 1e-5f) * a.ieg1[j] + a.iebe1[j], 0.f);
  }
  __syncthreads();
  if (tid < 128) {  // E2: 4 rows x 32, LN32 via width-32 shuffles
    int r = tid >> 5, jj = tid & 31;
    float u = a.ieb2[jj];
    for (int k = 0; k < 128; ++k) u += reg2[r * 128 + k] * a.iew2[k * 32 + jj];
    float ss = u, sq = u * u;
#pragma unroll
    for (int m = 16; m >= 1; m >>= 1) { ss += __shfl_xor(ss, m, 32); sq += __shfl_xor(sq, m, 32); }
    float mm = ss * (1.f / 32.f), vv = sq * (1.f / 32.f) - mm * mm;
    reg2[512 + r * 32 + jj] = fmaxf((u - mm) * rsqrtf(vv + 1e-5f) * a.ieg2[jj] + a.iebe2[jj], 0.f);
  }
  __syncthreads();
  if (tid < 16) {  // enc 4x4
    int r = tid >> 2, o = tid & 3;
    float u = a.ieb3[o];
    for (int k = 0; k < 32; ++k) u += reg2[512 + r * 32 + k] * a.iew3[k * 4 + o];
    reg2[640 + r * 4 + o] = u;
    gst(&a.enc_g[(b0e + r) * 4 + o], u);
  }
  __syncthreads();
  if (tid < 256) {  // values (softmax over size-1 axis == 1 -> att == values)
    int r = tid >> 6, v = tid & 63;
    float u = a.vb[v];
#pragma unroll
    for (int o = 0; o < 4; ++o) u += reg2[640 + r * 4 + o] * a.vw[o * 64 + v];
    s_values[r][v] = u;
  }
  drain_sync();
  signal(&slotE[g], 1u);

  if (g >= 8) {  // static w4 moments (only mid blocks need them)
    float q[14];
    if (tid < 256) {
      float wv[4] = {s_w4[tid], s_w4[256 + tid], s_w4[512 + tid], s_w4[768 + tid]};
      int idx = 0;
#pragma unroll
    for (int o = 0; o < 4; ++o) q[idx++] = wv[o];
#pragma unroll
    for (int o = 0; o < 4; ++o)
#pragma unroll
      for (int p = 0; p <= o; ++p) q[idx++] = wv[o] * wv[p];
    } else {
#pragma unroll
      for (int i = 0; i < 14; ++i) q[i] = 0.f;
    }
#pragma unroll
    for (int i = 0; i < 14; ++i) q[i] = wave_red_sum(q[i]);
    int w = tid >> 6;
    if (lane == 0) {
#pragma unroll
      for (int i = 0; i < 14; ++i) s_tmp[1][w * 16 + i] = q[i];
    }
    __syncthreads();
    if (tid < 14) {
      float S = 0.f;
#pragma unroll
      for (int w2 = 0; w2 < 8; ++w2) S += s_tmp[1][w2 * 16 + tid];
      s_stats[6 + tid] = S * (1.f / 256.f);
    }
    __syncthreads();
  }

  // ================= TICK LOOP ==============================================
  for (int t = 0; t < T_; ++t) {
    if (g < 8) {
      // strips: reduce pc rows r = g + 8i -> pc2[g][256]; then idle to slotC
      wait_mod8(slotA, g, (unsigned)(t + 1));
      int j = tid & 255, half = tid >> 8;
      float acc = 0.f;
#pragma unroll
      for (int i = 0; i < 16; ++i) {
        int r = g + 8 * (half * 16 + i);
        acc += gld(&a.pc[r * 256 + j]);
      }
      s_tmp[half][j] = acc;
      __syncthreads();
      if (tid < 256) gst(&a.pc2[g * 256 + tid], s_tmp[0][tid] + s_tmp[1][tid]);
      drain_sync();
      signal(&slotR[g], (unsigned)(t + 1));
    } else {
      // mid: cval + tick stats + mb/rb + own hbar column(s)
      wait_set(slotR, 8, (unsigned)(t + 1));
      {  // cval gather: 512 threads, 4 strips each
        int j = tid & 255, half = tid >> 8;
        float cp = 0.f;
#pragma unroll
        for (int s = 0; s < 4; ++s) cp += gld(&a.pc2[(half * 4 + s) * 256 + j]);
        s_tmp[half][j] = cp;
      }
      __syncthreads();
      {
        float cv = 0.f;
        if (tid < 256) {
          cv = a.syb1[tid] + s_tmp[0][tid] + s_tmp[1][tid];
          s_cval[tid] = cv;
        }
        float p[6];
        if (tid < 256) {
          p[0] = cv; p[1] = cv * cv;
          p[2] = cv * s_w4[tid]; p[3] = cv * s_w4[256 + tid];
          p[4] = cv * s_w4[512 + tid]; p[5] = cv * s_w4[768 + tid];
        } else {
#pragma unroll
          for (int i = 0; i < 6; ++i) p[i] = 0.f;
        }
        __syncthreads();  // s_tmp reads done before lane0 rewrites below
#pragma unroll
        for (int i = 0; i < 6; ++i) p[i] = wave_red_sum(p[i]);
        int w = tid >> 6;
        if (lane == 0) {
#pragma unroll
          for (int i = 0; i < 6; ++i) s_tmp[0][w * 8 + i] = p[i];
        }
        __syncthreads();
        if (tid < 6) {
          float S = 0.f;
#pragma unroll
          for (int w2 = 0; w2 < 8; ++w2) S += s_tmp[0][w2 * 8 + tid];
          s_stats[tid] = S * (1.f / 256.f);
        }
        __syncthreads();
      }
      if (t == 0) {  // encT[o][b] (lane-axis stride-1); gated on all encoders
        wait_set(slotE, 256, 1u);
        for (int i = tid; i < 4096; i += NTHR) {
          int b = i >> 2, o = i & 3;
          reg1[o * 1024 + b] = gld(&a.enc_g[i]);
        }
        __syncthreads();
      }
      {  // mb/rb for all 1024 b (2 per thread)
#pragma unroll
        for (int h2 = 0; h2 < 2; ++h2) {
          int b = h2 * 512 + tid;
          float e0 = reg1[b], e1v = reg1[1024 + b], e2v = reg1[2048 + b], e3v = reg1[3072 + b];
          float m = s_stats[0] + e0 * s_stats[6] + e1v * s_stats[7] + e2v * s_stats[8] + e3v * s_stats[9];
          float eu2 = s_stats[1] + 2.f * (e0 * s_stats[2] + e1v * s_stats[3] + e2v * s_stats[4] + e3v * s_stats[5]);
          float qf = e0 * e0 * s_stats[10]
                   + 2.f * e1v * e0 * s_stats[11] + e1v * e1v * s_stats[12]
                   + 2.f * e2v * e0 * s_stats[13] + 2.f * e2v * e1v * s_stats[14] + e2v * e2v * s_stats[15]
                   + 2.f * e3v * e0 * s_stats[16] + 2.f * e3v * e1v * s_stats[17]
                   + 2.f * e3v * e2v * s_stats[18] + e3v * e3v * s_stats[19];
          eu2 += qf;
          s_mbrb[b] = m;
          s_mbrb[1024 + b] = rsqrtf(eu2 - m * m + 1e-5f);
        }
        __syncthreads();
      }
      {  // hbar column(s): j = g; blocks 8..15 also j = g-8 (strips' cols)
        int ncol = (g < 16) ? 2 : 1;
        for (int c = 0; c < ncol; ++c) {
          int jj = c ? (g - 8) : g;
          float cj = s_cval[jj];
          float w0 = s_w4[jj], w1v = s_w4[256 + jj], w2v = s_w4[512 + jj], w3v = s_w4[768 + jj];
          float gj = a.syg[jj], bj = a.sybe[jj];
          float acc = 0.f;
#pragma unroll
          for (int h2 = 0; h2 < 2; ++h2) {
            int b = h2 * 512 + tid;
            float e0 = reg1[b], e1v = reg1[1024 + b], e2v = reg1[2048 + b], e3v = reg1[3072 + b];
            float u = cj + e0 * w0 + e1v * w1v + e2v * w2v + e3v * w3v;
            float y = (u - s_mbrb[b]) * s_mbrb[1024 + b] * gj + bj;
            acc += fmaxf(y, 0.f);
          }
          acc = wave_red_sum(acc);
          int w = tid >> 6;
          if (lane == 0) s_tmp[0][w] = acc;
          __syncthreads();
          if (tid == 0) {
            float S = 0.f;
#pragma unroll
            for (int w2 = 0; w2 < 8; ++w2) S += s_tmp[0][w2];
            gst(&a.hbar[jj], S * (1.f / 1024.f));
          }
          __syncthreads();
        }
      }
      drain_sync();
      signal(&slotC[g], (unsigned)(t + 1));
    }
    // everyone: wait all 248 hbar producers, then P3
    wait_set(slotC + 8, 248, (unsigned)(t + 1));
    if (tid < 256) s_hbar[tid] = gld(&a.hbar[tid]);
    __syncthreads();
    {  // npre from pinned syw2 (pad-17); s_tmp as [32][16]
      int nl = tid & 15, kq = tid >> 4;
      float u = 0.f;
#pragma unroll
      for (int kk = 0; kk < 8; ++kk) {
        int k = kq * 8 + kk;
        u += s_hbar[k] * s_syw2[k * 17 + nl];
      }
      ((float*)s_tmp)[kq * 16 + nl] = u;
    }
    __syncthreads();
    if (tid < 16) {
      float v = a.syb2[n0 + tid];
#pragma unroll
      for (int q2 = 0; q2 < 32; ++q2) v += ((float*)s_tmp)[q2 * 16 + tid];
#pragma unroll
      for (int m = 0; m < M_ - 1; ++m) s_pre[tid][m] = s_pre[tid][m + 1];
      s_pre[tid][M_ - 1] = v;
    }
    __syncthreads();
    {  // nm: 16 neurons x 32 lanes, strided j = q + 32k (conflict-free)
      int nl = tid >> 5, q = tid & 31;
      int n2 = n0 + nl;
      float pr[M_];
#pragma unroll
      for (int m = 0; m < M_; ++m) pr[m] = s_pre[nl][m];
      float u[4];
#pragma unroll
      for (int k = 0; k < 4; ++k) {
        int j = q + 32 * k;
        float uu = a.nb1[n2 * 128 + j];
#pragma unroll
        for (int m = 0; m < M_; ++m) uu += pr[m] * s_w1[(nl * M_ + m) * 128 + j];
        u[k] = uu;
      }
      float s = u[0] + u[1] + u[2] + u[3];
      float sq = u[0] * u[0] + u[1] * u[1] + u[2] * u[2] + u[3] * u[3];
#pragma unroll
      for (int m = 16; m >= 1; m >>= 1) { s += __shfl_xor(s, m, 32); sq += __shfl_xor(sq, m, 32); }
      float mm = s * (1.f / 128.f), vv = sq * (1.f / 128.f) - mm * mm;
      float ri = rsqrtf(vv + 1e-5f);
      float d = 0.f;
#pragma unroll
      for (int k = 0; k < 4; ++k) {
        int j = q + 32 * k;
        float y = fmaxf((u[k] - mm) * ri * a.ng[n2 * 128 + j] + a.nbe[n2 * 128 + j], 0.f);
        d += y * a.nw2[n2 * 128 + j];
      }
#pragma unroll
      for (int m = 16; m >= 1; m >>= 1) d += __shfl_xor(d, m, 32);
      if (q == 0) {
        float npost = d + a.nb2[n2];
#pragma unroll
        for (int m = 0; m < M_ - 1; ++m) s_post[nl][m] = s_post[nl][m + 1];
        s_post[nl][M_ - 1] = npost;
        s_pl[nl] = npost;
      }
    }
    __syncthreads();
    if (t < T_ - 1) {  // next pc partial
      int j = tid & 255, half = tid >> 8;
      float acc = 0.f;
#pragma unroll
      for (int r = 0; r < 8; ++r) {
        int n = half * 8 + r;
        acc += s_pl[n] * s_syw1[n * 256 + j];
      }
      s_tmp[half][j] = acc;
      __syncthreads();
      if (tid < 256) gst(&a.pc[g * 256 + tid], s_tmp[0][tid] + s_tmp[1][tid]);
    } else {  // flush final post rows
      if (tid < 160) {
        int r = tid / 10, m = tid - r * 10;
        gst(&a.postG[(n0 + r) * M_ + m], s_post[r][m]);
      }
    }
    drain_sync();
    signal(&slotA[g], (unsigned)(t + 2));
  }

  // ================= EPILOGUE ===============================================
  // strips: syncv (own 128 pairs) + scp partial in one stage
  if (g < 8) {
    wait_set(slotA, 256, 11u);
    if (tid < 128) {
      int p = g * 128 + tid;
      int i = a.pairs[p * 2], jn = a.pairs[p * 2 + 1];
      float dc = a.decay[p];
      float num = 0.f, den = 0.f;
#pragma unroll
      for (int l = 0; l < M_; ++l) {
        float r = expf(-dc * (float)(M_ - 1 - l));
        num += gld(&a.postG[i * M_ + l]) * r * gld(&a.postG[jn * M_ + l]);
        den += r;
      }
      s_tmp[0][tid] = num / (den + 1e-8f);
    }
    __syncthreads();
    float acc = 0.f;
    for (int i = 0; i < 128; ++i)
      acc += s_tmp[0][i] * a.rdw1[(64 + g * 128 + i) * 512 + tid];
    gst(&a.scp[g * 512 + tid], acc);
    drain_sync();
    signal(&slotR[g], 11u);
  }
  wait_set(slotR, 8, 11u);
  {  // readout for own 4 batch rows
    float* r1 = reg1;
    float* p2 = reg1 + 2048;
    float base = a.rdb1[tid];
#pragma unroll
    for (int s = 0; s < 8; ++s) base += gld(&a.scp[s * 512 + tid]);
    float u[4];
#pragma unroll
    for (int r = 0; r < 4; ++r) u[r] = base;
    for (int k = 0; k < 64; ++k) {
      float w = a.rdw1[k * 512 + tid];
#pragma unroll
      for (int r = 0; r < 4; ++r) u[r] += s_values[r][k] * w;
    }
    int wid = tid >> 6;
#pragma unroll
    for (int r = 0; r < 4; ++r) {
      float s = wave_red_sum(u[r]), sq = wave_red_sum(u[r] * u[r]);
      if (lane == 0) { s_tmp[0][r * 8 + wid] = s; s_tmp[1][r * 8 + wid] = sq; }
    }
    __syncthreads();
    float gg = a.rdg1[tid], bb = a.rdbe1[tid];
#pragma unroll
    for (int r = 0; r < 4; ++r) {
      float S = 0.f, S2 = 0.f;
#pragma unroll
      for (int w = 0; w < 8; ++w) { S += s_tmp[0][r * 8 + w]; S2 += s_tmp[1][r * 8 + w]; }
      float m = S * (1.f / 512.f), v = S2 * (1.f / 512.f) - m * m;
      r1[r * 512 + tid] = fmaxf((u[r] - m) * rsqrtf(v + 1e-5f) * gg + bb, 0.f);
    }
    __syncthreads();
    int o = tid & 63, kq = tid >> 6;
    float u2[4] = {0.f, 0.f, 0.f, 0.f};
#pragma unroll
    for (int kk = 0; kk < 64; ++kk) {
      int k = kq * 64 + kk;
      float w = a.rdw2[k * 64 + o];
#pragma unroll
      for (int r = 0; r < 4; ++r) u2[r] += r1[r * 512 + k] * w;
    }
#pragma unroll
    for (int r = 0; r < 4; ++r) p2[(kq * 4 + r) * 64 + o] = u2[r];
    __syncthreads();
    if (tid < 256) {
      int r = tid >> 6, o2 = tid & 63;
      float v = a.rdb2[o2];
#pragma unroll
      for (int q = 0; q < 8; ++q) v += p2[(q * 4 + r) * 64 + o2];
      float s = wave_red_sum(v), sq = wave_red_sum(v * v);
      float m = s * (1.f / 64.f), var = sq * (1.f / 64.f) - m * m;
      reg2[r * 64 + o2] = fmaxf((v - m) * rsqrtf(var + 1e-5f) * a.rdg2[o2] + a.rdbe2[o2], 0.f);
    }
    __syncthreads();
    if (tid < 40) {
      int r = tid / 10, o3 = tid - r * 10;
      float acc = a.rdb3[o3];
#pragma unroll
      for (int k = 0; k < 64; ++k) acc += reg2[r * 64 + k] * a.rdw3[k * 10 + o3];
      a.out[(b0e + r) * 10 + o3] = acc;
    }
  }
}

extern "C" void kernel_launch(void* const* d_in, const int* in_sizes, int n_in,
                              void* d_out, int out_size, void* d_ws, size_t ws_size,
                              hipStream_t stream) {
  MArgs a;
  a.x     = (const float*)d_in[0];
  a.post0 = (const float*)d_in[1];
  a.pre0  = (const float*)d_in[2];
  a.pairs = (const int*)d_in[3];
  a.decay = (const float*)d_in[4];
  a.iew1  = (const float*)d_in[5];
  a.ieb1  = (const float*)d_in[6];
  a.ieg1  = (const float*)d_in[7];
  a.iebe1 = (const float*)d_in[8];
  a.iew2  = (const float*)d_in[9];
  a.ieb2  = (const float*)d_in[10];
  a.ieg2  = (const float*)d_in[11];
  a.iebe2 = (const float*)d_in[12];
  a.iew3  = (const float*)d_in[13];
  a.ieb3  = (const float*)d_in[14];
  a.syw1  = (const float*)d_in[15];
  a.syb1  = (const float*)d_in[16];
  a.syg   = (const float*)d_in[17];
  a.sybe  = (const float*)d_in[18];
  a.syw2  = (const float*)d_in[19];
  a.syb2  = (const float*)d_in[20];
  a.nw1   = (const float*)d_in[21];
  a.nb1   = (const float*)d_in[22];
  a.ng    = (const float*)d_in[23];
  a.nbe   = (const float*)d_in[24];
  a.nw2   = (const float*)d_in[25];
  a.nb2   = (const float*)d_in[26];
  a.vw    = (const float*)d_in[29];
  a.vb    = (const float*)d_in[30];
  a.rdw1  = (const float*)d_in[33];
  a.rdb1  = (const float*)d_in[34];
  a.rdg1  = (const float*)d_in[35];
  a.rdbe1 = (const float*)d_in[36];
  a.rdw2  = (const float*)d_in[37];
  a.rdb2  = (const float*)d_in[38];
  a.rdg2  = (const float*)d_in[39];
  a.rdbe2 = (const float*)d_in[40];
  a.rdw3  = (const float*)d_in[41];
  a.rdb3  = (const float*)d_in[42];
  a.out = (float*)d_out;

  float* ws = (float*)d_ws;
  a.pc    = ws;                 // 65536
  a.pc2   = ws + 65536;         // 2048
  a.enc_g = ws + 67584;         // 4096
  a.hbar  = ws + 71680;         // 256
  a.postG = ws + 71936;         // 40960
  a.scp   = ws + 112896;        // 4096
  a.bar   = (unsigned*)(ws + 117000);  // 1024 uints

  k_init<<<1, 1024, 0, stream>>>(a.bar);
  k_mega<<<NBLK, NTHR, 0, stream>>>(a);
}